// Round 12
// baseline (136.784 us; speedup 1.0000x reference)
//
#include <hip/hip_runtime.h>
#include <math.h>

#define DEV static __device__ __forceinline__

// ---- problem dims ----
constexpr int NB    = 16;
constexpr int BATCH = 32;
constexpr int DDIM  = 512;
constexpr int RK    = 64;
constexpr int LAY   = 5;
constexpr int MM    = 80;
constexpr int TLS   = NB * BATCH * DDIM;

constexpr float ETA_W   = 0.015f;
constexpr float LAM_C   = 0.65f, LAM_R = 0.35f;
constexpr float THETA0  = 0.5f;
constexpr float SPEC_MIN = 0.3f, SPEC_MAX = 4.0f;
constexpr float DW_CLIP = 5.0f;
constexpr float W_MAX   = 45.254833995939045f;
constexpr float RSQ_D   = 0.044194173824159216f;

// ---- output layout (floats) ----
constexpr int OUT_MSE  = 0;
constexpr int OUT_EDGE = 1;                       // 1280
constexpr int OUT_A    = 1281;                    // 2621440
constexpr int OUT_B    = OUT_A + MM * DDIM * RK;  // 2622721
constexpr int OUT_T    = OUT_B + MM * DDIM * RK;  // 5244161

// ---- scratch parked inside output regions (consumed before k_final) ----
constexpr int SCR_GP   = 1284;        // gram partials (OUT_A region), dead after k_power
constexpr int SCR_YV   = 2622724;     // Yv 80*2048 fl (OUT_B region, 16B aligned)
constexpr int SCR_VIN  = 5244164;     // V_in sums (OUT_T region, 16B aligned)

// ---- ws layout (floats) ----
// NORMB b-major: ws[WS_NORMB + b*1280 + h*256 + j*16 + i]
constexpr int WS_NORMB  = 0;        // 40960
constexpr int WS_TVN    = 40960;    // 32
constexpr int WS_TVM    = 41000;    // 512
constexpr int WS_COEF   = 41600;    // 96
constexpr int WS_SCALE  = 41700;    // 80
constexpr int WS_Y0P    = 41800;    // 20480
constexpr int WS_VM     = 62300;    // 40960
constexpr int WS_P      = 103300;   // 5120
constexpr int WS_Q      = 108450;   // 5120
constexpr int WS_GC     = 113600;   // 40960

DEV float wave_reduce(float v) {
  #pragma unroll
  for (int o = 32; o > 0; o >>= 1) v += __shfl_down(v, o, 64);
  return v;
}

DEV float block_reduce_512(float v, float* sred) {
  v = wave_reduce(v);
  __syncthreads();
  if ((threadIdx.x & 63) == 0) sred[threadIdx.x >> 6] = v;
  __syncthreads();
  float s = 0.f;
  #pragma unroll
  for (int k = 0; k < 8; ++k) s += sred[k];
  return s;
}

DEV float bcast_lane(float v, int lane) {
  return __int_as_float(__builtin_amdgcn_readlane(__float_as_int(v), lane));
}

// ================ k_vin: vin_norm | tvnorm | mse | TVM (small LDS, high occ) ================
__global__ __launch_bounds__(256, 8) void k_vin(const float* __restrict__ V,
    const float* __restrict__ yh, const float* __restrict__ ys,
    float* __restrict__ out, float* __restrict__ ws) {
  __shared__ float smem[3072];   // 12.3 KB
  int bid = blockIdx.x, t = threadIdx.x;
  if (bid < 2560) {
    float* nbuf = smem;                 // [16][128]
    float* vbuf = smem + 2048;          // [2][512]
    int b = bid & 31, j = (bid >> 5) & 15, hh = bid >> 9;
    const float* base = V + (size_t)(((hh*16 + j)*16)*32 + b) * 512;
    int g = t >> 7, u = t & 127;
    float vx = 0.f, vy = 0.f, vz = 0.f, vw = 0.f;
    #pragma unroll
    for (int io = 0; io < 8; ++io) {
      int i = io * 2 + g;
      float4 v = ((const float4*)(base + (size_t)i * 16384))[u];
      nbuf[i * 128 + u] = v.x*v.x + v.y*v.y + v.z*v.z + v.w*v.w;
      vx += v.x; vy += v.y; vz += v.z; vw += v.w;
    }
    vbuf[g * 512 + u * 4 + 0] = vx;
    vbuf[g * 512 + u * 4 + 1] = vy;
    vbuf[g * 512 + u * 4 + 2] = vz;
    vbuf[g * 512 + u * 4 + 3] = vw;
    __syncthreads();
    {
      float2 o;
      o.x = vbuf[2 * t]     + vbuf[512 + 2 * t];
      o.y = vbuf[2 * t + 1] + vbuf[512 + 2 * t + 1];
      ((float2*)(out + SCR_VIN + (size_t)((hh*16 + j)*32 + b) * 512))[t] = o;
    }
    int w = t >> 6, lane = t & 63;
    #pragma unroll
    for (int k = 0; k < 4; ++k) {
      int i = w * 4 + k;
      float s = nbuf[i * 128 + lane] + nbuf[i * 128 + lane + 64];
      s = wave_reduce(s);
      if (lane == 0)
        ws[WS_NORMB + (size_t)b * 1280 + (hh*16 + j) * 16 + i] = sqrtf(s);
    }
  } else if (bid < 2592) {
    int b = bid - 2560;
    float2 a = ((const float2*)(yh + (size_t)b * 512))[t];
    float2 c = ((const float2*)(ys + (size_t)b * 512))[t];
    float d0 = c.x - a.x, d1 = c.y - a.y;
    float s = d0*d0 + d1*d1;
    s = wave_reduce(s);
    if ((t & 63) == 0) smem[t >> 6] = s;
    __syncthreads();
    if (t == 0)
      ws[WS_TVN + b] = sqrtf(smem[0]+smem[1]+smem[2]+smem[3]) * RSQ_D;
  } else if (bid == 2592) {
    float s = 0.f;
    for (int i = t; i < 4096; i += 256) {
      float4 a = ((const float4*)yh)[i], b = ((const float4*)ys)[i];
      float d0 = b.x-a.x, d1 = b.y-a.y, d2 = b.z-a.z, d3 = b.w-a.w;
      s += d0*d0 + d1*d1 + d2*d2 + d3*d3;
    }
    s = wave_reduce(s);
    if ((t & 63) == 0) smem[t >> 6] = s;
    __syncthreads();
    if (t == 0)
      out[OUT_MSE] = (smem[0]+smem[1]+smem[2]+smem[3]) * (1.f/16384.f);
  } else {
    float s0 = 0.f, s1 = 0.f;
    #pragma unroll 4
    for (int b = 0; b < 32; ++b) {
      s0 += ys[b*512 + t]       - yh[b*512 + t];
      s1 += ys[b*512 + t + 256] - yh[b*512 + t + 256];
    }
    ws[WS_TVM + t]       = s0 * (RSQ_D / 32.f);
    ws[WS_TVM + t + 256] = s1 * (RSQ_D / 32.f);
  }
}

// ================ k_gyv: gram partials (640 blocks) + Yv (160 blocks) ================
__global__ __launch_bounds__(256) void k_gyv(const float* __restrict__ Aw,
    const float* __restrict__ Bww, float* __restrict__ out, float* __restrict__ ws) {
  __shared__ float smem[8448];   // 33.8 KB (gram only)
  int bid = blockIdx.x, t = threadIdx.x;
  if (bid < 640) {
    // ---- Gram partials (R8-proven, pitch 64) ----
    float* tile = smem;
    float (*y0s)[64] = (float(*)[64])(smem + 8192);
    int slice = bid & 3, side = (bid >> 2) & 1, m = bid >> 3;
    const float* src = (side ? Bww : Aw) + (size_t)m * 32768 + slice * 8192;
    #pragma unroll
    for (int k = 0; k < 8; ++k)
      ((float4*)tile)[t + k * 256] = ((const float4*)src)[t + k * 256];
    __syncthreads();
    {
      int r = t & 63, q = t >> 6;
      float s = 0.f;
      #pragma unroll 8
      for (int dd = q * 32; dd < q * 32 + 32; ++dd) s += tile[dd * 64 + r];
      y0s[q][r] = s;
    }
    __syncthreads();
    if (side == 0 && t < 64)
      ws[WS_Y0P + (m * 4 + slice) * 64 + t] = y0s[0][t] + y0s[1][t] + y0s[2][t] + y0s[3][t];
    float acc[4][4];
    #pragma unroll
    for (int i = 0; i < 4; ++i)
      #pragma unroll
      for (int k = 0; k < 4; ++k) acc[i][k] = 0.f;
    int r1 = (t >> 4) * 4, r2 = (t & 15) * 4;
    #pragma unroll 4
    for (int dd = 0; dd < 128; ++dd) {
      float4 a1 = *(const float4*)&tile[dd * 64 + r1];
      float4 a2 = *(const float4*)&tile[dd * 64 + r2];
      float av[4] = {a1.x, a1.y, a1.z, a1.w};
      float bv[4] = {a2.x, a2.y, a2.z, a2.w};
      #pragma unroll
      for (int i = 0; i < 4; ++i)
        #pragma unroll
        for (int k = 0; k < 4; ++k) acc[i][k] += av[i] * bv[k];
    }
    float* outp = out + SCR_GP + (size_t)((m * 2 + side) * 4 + slice) * 4096;
    #pragma unroll
    for (int i = 0; i < 4; ++i) {
      float4 v; v.x = acc[i][0]; v.y = acc[i][1]; v.z = acc[i][2]; v.w = acc[i][3];
      *(float4*)&outp[(r1 + i) * 64 + r2] = v;
    }
  } else {
    // ---- Yv = Vin @ B (lane = r, coalesced B rows, no LDS) ----
    int bid0 = bid - 640;                 // m*2 + half
    int m = bid0 >> 1, half = bid0 & 1;
    int w = t >> 6, r = t & 63;
    int b0 = half * 16 + w * 4;
    const float* Bm = Bww + (size_t)m * 32768;
    const float* Vm = out + SCR_VIN + (size_t)m * 16384;
    float acc0 = 0.f, acc1 = 0.f, acc2 = 0.f, acc3 = 0.f;
    #pragma unroll 2
    for (int d = 0; d < 512; d += 4) {
      float br0 = Bm[(d+0)*64 + r];
      float br1 = Bm[(d+1)*64 + r];
      float br2 = Bm[(d+2)*64 + r];
      float br3 = Bm[(d+3)*64 + r];
      float4 v0 = *(const float4*)(Vm + (b0+0)*512 + d);
      float4 v1 = *(const float4*)(Vm + (b0+1)*512 + d);
      float4 v2 = *(const float4*)(Vm + (b0+2)*512 + d);
      float4 v3 = *(const float4*)(Vm + (b0+3)*512 + d);
      acc0 += br0*v0.x + br1*v0.y + br2*v0.z + br3*v0.w;
      acc1 += br0*v1.x + br1*v1.y + br2*v1.z + br3*v1.w;
      acc2 += br0*v2.x + br1*v2.y + br2*v2.z + br3*v2.w;
      acc3 += br0*v3.x + br1*v3.y + br2*v3.z + br3*v3.w;
    }
    float* Yv = out + SCR_YV + (size_t)m * 2048;
    Yv[(b0+0)*64 + r] = acc0;
    Yv[(b0+1)*64 + r] = acc1;
    Yv[(b0+2)*64 + r] = acc2;
    Yv[(b0+3)*64 + r] = acc3;
  }
}

// ================ power iteration (register-resident) ================
__global__ __launch_bounds__(64, 1) void k_power(const float* __restrict__ out,
                                                 float* __restrict__ ws) {
  int m = blockIdx.x;
  int r = threadIdx.x;
  const float* gp = out + SCR_GP + (size_t)(m * 2 + 0) * 16384;
  const float* hp = out + SCR_GP + (size_t)(m * 2 + 1) * 16384;
  float Gc[64], Hc[64];
  #pragma unroll
  for (int c4 = 0; c4 < 16; ++c4) {
    const float* gb = gp + r * 64 + c4 * 4;
    float4 g0 = *(const float4*)(gb);
    float4 g1 = *(const float4*)(gb + 4096);
    float4 g2 = *(const float4*)(gb + 8192);
    float4 g3 = *(const float4*)(gb + 12288);
    Gc[c4*4+0] = g0.x+g1.x+g2.x+g3.x;
    Gc[c4*4+1] = g0.y+g1.y+g2.y+g3.y;
    Gc[c4*4+2] = g0.z+g1.z+g2.z+g3.z;
    Gc[c4*4+3] = g0.w+g1.w+g2.w+g3.w;
    const float* hb = hp + r * 64 + c4 * 4;
    float4 h0 = *(const float4*)(hb);
    float4 h1 = *(const float4*)(hb + 4096);
    float4 h2 = *(const float4*)(hb + 8192);
    float4 h3 = *(const float4*)(hb + 12288);
    Hc[c4*4+0] = h0.x+h1.x+h2.x+h3.x;
    Hc[c4*4+1] = h0.y+h1.y+h2.y+h3.y;
    Hc[c4*4+2] = h0.z+h1.z+h2.z+h3.z;
    Hc[c4*4+3] = h0.w+h1.w+h2.w+h3.w;
  }
  float y = (ws[WS_Y0P + (m*4+0)*64 + r] + ws[WS_Y0P + (m*4+1)*64 + r] +
             ws[WS_Y0P + (m*4+2)*64 + r] + ws[WS_Y0P + (m*4+3)*64 + r]) * RSQ_D;
  for (int it = 0; it < 20; ++it) {
    float z0 = 0.f, z1 = 0.f, z2 = 0.f, z3 = 0.f;
    #pragma unroll
    for (int c = 0; c < 16; ++c) {
      z0 = fmaf(Hc[c],      bcast_lane(y, c),      z0);
      z1 = fmaf(Hc[c + 16], bcast_lane(y, c + 16), z1);
      z2 = fmaf(Hc[c + 32], bcast_lane(y, c + 32), z2);
      z3 = fmaf(Hc[c + 48], bcast_lane(y, c + 48), z3);
    }
    float z = (z0 + z1) + (z2 + z3);
    float t0 = 0.f, t1 = 0.f, t2 = 0.f, t3 = 0.f;
    #pragma unroll
    for (int c = 0; c < 16; ++c) {
      t0 = fmaf(Gc[c],      bcast_lane(z, c),      t0);
      t1 = fmaf(Gc[c + 16], bcast_lane(z, c + 16), t1);
      t2 = fmaf(Gc[c + 32], bcast_lane(z, c + 32), t2);
      t3 = fmaf(Gc[c + 48], bcast_lane(z, c + 48), t3);
    }
    float tt = (t0 + t1) + (t2 + t3);
    float zt = z * tt;
    #pragma unroll
    for (int o = 32; o > 0; o >>= 1) zt += __shfl_xor(zt, o, 64);
    y = tt / (sqrtf(zt) + 1e-12f);
  }
  float z0 = 0.f, z1 = 0.f, z2 = 0.f, z3 = 0.f;
  #pragma unroll
  for (int c = 0; c < 16; ++c) {
    z0 = fmaf(Hc[c],      bcast_lane(y, c),      z0);
    z1 = fmaf(Hc[c + 16], bcast_lane(y, c + 16), z1);
    z2 = fmaf(Hc[c + 32], bcast_lane(y, c + 32), z2);
    z3 = fmaf(Hc[c + 48], bcast_lane(y, c + 48), z3);
  }
  float z = (z0 + z1) + (z2 + z3);
  float yz = y * z;
  #pragma unroll
  for (int o = 32; o > 0; o >>= 1) yz += __shfl_xor(yz, o, 64);
  if (r == 0)
    ws[WS_SCALE + m] = fminf(fmaxf(sqrtf(yz), SPEC_MIN), SPEC_MAX);
}

// ================ k_vw: A-rows in registers, Yv via LDS broadcast ================
// NOTE: no min-waves clause — ar[64] + transients must stay in VGPRs (no scratch).
__global__ __launch_bounds__(512) void k_vw(const float* __restrict__ Aw,
    float* __restrict__ out, float* __restrict__ ws) {
  __shared__ float ubuf[2176];   // C[1280] then Yv[32][68]
  __shared__ float gcol[512];
  __shared__ float sred[8];
  __shared__ float coefs[96];
  int m = blockIdx.x;
  int t = threadIdx.x;
  int hh = m >> 4, j = m & 15;
  const float* A1  = Aw + (size_t)m * 32768;
  const float* Vin = out + SCR_VIN + (size_t)m * 16384;
  const float* YvG = out + SCR_YV + (size_t)m * 2048;

  // ---- prologue: coef chain (redundant per block, coalesced) ----
  if (t < 256) {
    #pragma unroll
    for (int h = 0; h < 5; ++h) {
      float n = 0.f;
      #pragma unroll 8
      for (int b = 0; b < 32; ++b)
        n += ws[WS_NORMB + (size_t)b * 1280 + h * 256 + t];
      n *= (1.f / 32.f);
      float s = n;
      s += __shfl_xor(s, 1, 64);
      s += __shfl_xor(s, 2, 64);
      s += __shfl_xor(s, 4, 64);
      s += __shfl_xor(s, 8, 64);
      ubuf[h * 256 + t] = ws[WS_SCALE + h * 16 + (t >> 4)] * n / (s + 1e-9f);
    }
    if (t < 16) coefs[80 + t] = (t == 0) ? 1.f : 0.f;
  }
  __syncthreads();
  if (t < 16) {
    for (int h = 4; h >= 0; --h) {
      float s = 0.f;
      #pragma unroll
      for (int jj = 0; jj < 16; ++jj)
        s += ubuf[h * 256 + jj * 16 + t] * coefs[(h + 1) * 16 + jj];
      coefs[h * 16 + t] = s;
    }
  }
  __syncthreads();
  if (m == 0) {
    if (t < 256) {
      float tvs = 0.f;
      #pragma unroll
      for (int b = 0; b < 32; ++b) tvs += ws[WS_TVN + b];
      float tvmean = tvs * (1.f / 32.f);
      #pragma unroll
      for (int h = 0; h < 5; ++h)
        out[OUT_EDGE + h * 256 + t] = ubuf[h * 256 + t] * coefs[(h + 1) * 16 + (t >> 4)] * tvmean;
    }
    if (t < 96) ws[WS_COEF + t] = coefs[t];
  }
  float coefval = coefs[(hh + 1) * 16 + j];
  __syncthreads();   // protect ubuf overwrite (edges done)

  // ---- Yv -> LDS [b][68] ----
  {
    int b = t >> 4, r0 = (t & 15) * 4;
    float4 y4 = *(const float4*)(YvG + t * 4);
    *(float4*)&ubuf[b * 68 + r0] = y4;
  }
  __syncthreads();
  if (t < 64) {
    float s = 0.f;
    #pragma unroll 8
    for (int b = 0; b < 32; ++b) s += ubuf[b * 68 + t];
    ws[WS_P + m * 64 + t] = s * (1.f / 32.f);
  }
  // ---- A row d into registers (per-thread contiguous, L1-friendly) ----
  int d = t;
  float ar[64];
  #pragma unroll
  for (int k = 0; k < 16; ++k)
    *(float4*)&ar[k * 4] = *(const float4*)(A1 + d * 64 + k * 4);
  // ---- Vin stats ----
  float tmean, ssin, ssvm;
  {
    float sv = 0.f, sq = 0.f;
    #pragma unroll 4
    for (int b = 0; b < 32; ++b) {
      float v = Vin[b * 512 + d];
      sv += v; sq += v * v;
    }
    float vmean = sv * (1.f / 32.f);
    tmean = coefval * ws[WS_TVM + d];
    ws[WS_VM + m * 512 + d] = vmean;
    ssin = block_reduce_512(sq, sred) * (1.f / 32.f);
    ssvm = block_reduce_512(vmean * vmean, sred);
  }
  // ---- VW[b][d] = Yv[b]·A-row(d); tanh stats per-d exact ----
  float gs = 0.f, vga = 0.f, fpa = 0.f;
  for (int b = 0; b < 32; ++b) {
    const float* yb = &ubuf[b * 68];
    float a0 = 0.f, a1 = 0.f, a2 = 0.f, a3 = 0.f;
    #pragma unroll
    for (int k = 0; k < 4; ++k) {
      float4 y0 = *(const float4*)&yb[k * 16 + 0];
      float4 y1 = *(const float4*)&yb[k * 16 + 4];
      float4 y2 = *(const float4*)&yb[k * 16 + 8];
      float4 y3 = *(const float4*)&yb[k * 16 + 12];
      a0 += ar[k*16+ 0]*y0.x + ar[k*16+ 1]*y0.y + ar[k*16+ 2]*y0.z + ar[k*16+ 3]*y0.w;
      a1 += ar[k*16+ 4]*y1.x + ar[k*16+ 5]*y1.y + ar[k*16+ 6]*y1.z + ar[k*16+ 7]*y1.w;
      a2 += ar[k*16+ 8]*y2.x + ar[k*16+ 9]*y2.y + ar[k*16+10]*y2.z + ar[k*16+11]*y2.w;
      a3 += ar[k*16+12]*y3.x + ar[k*16+13]*y3.y + ar[k*16+14]*y3.z + ar[k*16+15]*y3.w;
    }
    float vw = (a0 + a1) + (a2 + a3);
    float x = fminf(fmaxf(vw * 2.f, -40.f), 40.f);
    float e = __expf(x);
    float vo = (e - 1.f) / (e + 1.f);
    float fp = 1.f - vo * vo;
    gs  += vo * vo;
    vga += vo * fp;
    fpa += fp;
  }
  float goodness = block_reduce_512(gs, sred) * (1.f / 32.f);
  float delta = goodness - THETA0 * (ssin + 1e-9f);
  {
    float g = LAM_C * delta * vga * (1.f / 32.f) + LAM_R * tmean * (fpa * (1.f / 32.f));
    float gn2 = block_reduce_512(g * g, sred);
    float gnorm = sqrtf(gn2) * sqrtf(ssvm);
    float clipf = gnorm > DW_CLIP ? DW_CLIP / (gnorm + 1e-12f) : 1.f;
    float gcv = g * clipf;
    ws[WS_GC + m * 512 + d] = gcv;
    gcol[d] = gcv;
  }
  __syncthreads();
  // ---- q[r] = sum_d gcol[d]*A[d][r] (coalesced A re-read; ubuf reused) ----
  {
    int r = t & 63, dq = t >> 6;
    float s = 0.f;
    #pragma unroll 4
    for (int k = 0; k < 64; ++k) {
      int dd = dq * 64 + k;
      s += gcol[dd] * A1[dd * 64 + r];
    }
    ubuf[dq * 64 + r] = s;
  }
  __syncthreads();
  if (t < 64) {
    float s = 0.f;
    #pragma unroll
    for (int p8 = 0; p8 < 8; ++p8) s += ubuf[p8 * 64 + t];
    ws[WS_Q + m * 64 + t] = s;
  }
}

// ================ final: T write + Adam update (float4 loads) ================
constexpr int TW_BLOCKS = 1536;
constexpr int AD_HALF4  = 655360;

__global__ __launch_bounds__(256) void k_final(const float* __restrict__ yh,
    const float* __restrict__ ys,
    const float* __restrict__ Aw, const float* __restrict__ Bww,
    const float* __restrict__ mA, const float* __restrict__ vA,
    const float* __restrict__ mB, const float* __restrict__ vB,
    const float* __restrict__ ws, float* __restrict__ out) {
  int bid = blockIdx.x, t = threadIdx.x;
  if (bid < TW_BLOCKS) {
    int g0 = (bid * 256 + t) * 4;
    int li = g0 >> 14;
    int bd = g0 & 16383;
    float4 a = *(const float4*)(yh + bd);
    float4 b = *(const float4*)(ys + bd);
    float cf = ws[WS_COEF + li] * RSQ_D;
    out[OUT_T + g0 + 0] = cf * (b.x - a.x);
    out[OUT_T + g0 + 1] = cf * (b.y - a.y);
    out[OUT_T + g0 + 2] = cf * (b.z - a.z);
    out[OUT_T + g0 + 3] = cf * (b.w - a.w);
    return;
  }
  int idx = (bid - TW_BLOCKS) * 256 + t;
  bool isB = idx >= AD_HALF4;
  int e = (isB ? idx - AD_HALF4 : idx) * 4;
  int m = e >> 15;
  int rem = e & 32767;
  int d = rem >> 6;
  int r = rem & 63;
  float4 g4;
  const float *w0, *m0, *v0;
  int obase;
  if (!isB) {
    float gc = ws[WS_GC + m * 512 + d];
    float4 p = *(const float4*)&ws[WS_P + m * 64 + r];
    g4.x = gc * p.x; g4.y = gc * p.y; g4.z = gc * p.z; g4.w = gc * p.w;
    w0 = Aw; m0 = mA; v0 = vA; obase = OUT_A;
  } else {
    float vm = ws[WS_VM + m * 512 + d];
    float4 q = *(const float4*)&ws[WS_Q + m * 64 + r];
    g4.x = vm * q.x; g4.y = vm * q.y; g4.z = vm * q.z; g4.w = vm * q.w;
    w0 = Bww; m0 = mB; v0 = vB; obase = OUT_B;
  }
  float4 a4 = *(const float4*)&w0[e];
  float4 mm4 = *(const float4*)&m0[e];
  float4 vv4 = *(const float4*)&v0[e];
  float ga[4] = {g4.x, g4.y, g4.z, g4.w};
  float aa[4] = {a4.x, a4.y, a4.z, a4.w};
  float ma[4] = {mm4.x, mm4.y, mm4.z, mm4.w};
  float va[4] = {vv4.x, vv4.y, vv4.z, vv4.w};
  #pragma unroll
  for (int i = 0; i < 4; ++i) {
    float g = ga[i];
    float mn = 0.9f * ma[i] + 0.1f * g;
    float vn = 0.999f * va[i] + 0.001f * g * g;
    float u = aa[i] - ETA_W * (mn * 10.f) / (sqrtf(vn * 1000.f) + 1e-8f);
    u = fminf(fmaxf(u, -W_MAX), W_MAX);
    out[obase + e + i] = u;
  }
}

extern "C" void kernel_launch(void* const* d_in, const int* in_sizes, int n_in,
                              void* d_out, int out_size, void* d_ws, size_t ws_size,
                              hipStream_t stream) {
  (void)in_sizes; (void)n_in; (void)out_size; (void)ws_size;
  const float* Yh = (const float*)d_in[0];
  const float* Ys = (const float*)d_in[1];
  const float* V  = (const float*)d_in[2];
  const float* Aw = (const float*)d_in[3];
  const float* Bw = (const float*)d_in[4];
  const float* mA = (const float*)d_in[5];
  const float* vA = (const float*)d_in[6];
  const float* mB = (const float*)d_in[7];
  const float* vB = (const float*)d_in[8];
  float* out = (float*)d_out;
  float* ws  = (float*)d_ws;

  k_vin<<<2594, 256, 0, stream>>>(V, Yh, Ys, out, ws);
  k_gyv<<<800, 256, 0, stream>>>(Aw, Bw, out, ws);
  k_power<<<80, 64, 0, stream>>>(out, ws);
  k_vw<<<80, 512, 0, stream>>>(Aw, out, ws);
  k_final<<<TW_BLOCKS + 2 * (AD_HALF4 / 256), 256, 0, stream>>>(
      Yh, Ys, Aw, Bw, mA, vA, mB, vB, ws, out);
}

// Round 13
// 115.523 us; speedup vs baseline: 1.1840x; 1.1840x over previous
//
#include <hip/hip_runtime.h>
#include <math.h>

#define DEV static __device__ __forceinline__

// ---- problem dims ----
constexpr int NB    = 16;
constexpr int BATCH = 32;
constexpr int DDIM  = 512;
constexpr int RK    = 64;
constexpr int LAY   = 5;
constexpr int MM    = 80;
constexpr int TLS   = NB * BATCH * DDIM;

constexpr float ETA_W   = 0.015f;
constexpr float LAM_C   = 0.65f, LAM_R = 0.35f;
constexpr float THETA0  = 0.5f;
constexpr float SPEC_MIN = 0.3f, SPEC_MAX = 4.0f;
constexpr float DW_CLIP = 5.0f;
constexpr float W_MAX   = 45.254833995939045f;
constexpr float RSQ_D   = 0.044194173824159216f;

// ---- output layout (floats) ----
constexpr int OUT_MSE  = 0;
constexpr int OUT_EDGE = 1;                       // 1280
constexpr int OUT_A    = 1281;                    // 2621440
constexpr int OUT_B    = OUT_A + MM * DDIM * RK;  // 2622721
constexpr int OUT_T    = OUT_B + MM * DDIM * RK;  // 5244161

// ---- scratch parked inside output regions (consumed before k_final) ----
constexpr int SCR_GP   = 1284;        // gram partials (OUT_A), dead after k_pyv
constexpr int SCR_YV   = 2622724;     // Yv 80*2048 fl (OUT_B), dead after k_vw
constexpr int SCR_VIN  = 5244164;     // V_in sums (OUT_T), dead after k_vw

// ---- ws layout (floats) ----
// NORMB b-major: ws[WS_NORMB + b*1280 + h*256 + j*16 + i]
constexpr int WS_NORMB  = 0;        // 40960
constexpr int WS_TVN    = 40960;    // 32
constexpr int WS_TVM    = 41000;    // 512
constexpr int WS_COEF   = 41600;    // 96
constexpr int WS_SCALE  = 41700;    // 80
constexpr int WS_Y0P    = 41800;    // 20480
constexpr int WS_VM     = 62300;    // 40960
constexpr int WS_P      = 103300;   // 5120
constexpr int WS_Q      = 108450;   // 5120
constexpr int WS_GC     = 113600;   // 40960

DEV float wave_reduce(float v) {
  #pragma unroll
  for (int o = 32; o > 0; o >>= 1) v += __shfl_down(v, o, 64);
  return v;
}

DEV float block_reduce_512(float v, float* sred) {
  v = wave_reduce(v);
  __syncthreads();
  if ((threadIdx.x & 63) == 0) sred[threadIdx.x >> 6] = v;
  __syncthreads();
  float s = 0.f;
  #pragma unroll
  for (int k = 0; k < 8; ++k) s += sred[k];
  return s;
}

DEV float bcast_lane(float v, int lane) {
  return __int_as_float(__builtin_amdgcn_readlane(__float_as_int(v), lane));
}

// ================ stage1: vin | tvnorm | mse | TVM | gram — one parallel pool ================
__global__ __launch_bounds__(256) void k_stage1(const float* __restrict__ V,
    const float* __restrict__ yh, const float* __restrict__ ys,
    const float* __restrict__ Aw, const float* __restrict__ Bww,
    float* __restrict__ out, float* __restrict__ ws) {
  __shared__ float smem[8448];   // 33.8 KB union (gram tile is the max user)
  int bid = blockIdx.x, t = threadIdx.x;
  if (bid < 2560) {
    // ---- V_in sums + per-edge norms (float4 loads) ----
    float* nbuf = smem;                 // [16][128]
    float* vbuf = smem + 2048;          // [2][512]
    int b = bid & 31, j = (bid >> 5) & 15, hh = bid >> 9;
    const float* base = V + (size_t)(((hh*16 + j)*16)*32 + b) * 512;
    int g = t >> 7, u = t & 127;
    float vx = 0.f, vy = 0.f, vz = 0.f, vw = 0.f;
    #pragma unroll
    for (int io = 0; io < 8; ++io) {
      int i = io * 2 + g;
      float4 v = ((const float4*)(base + (size_t)i * 16384))[u];
      nbuf[i * 128 + u] = v.x*v.x + v.y*v.y + v.z*v.z + v.w*v.w;
      vx += v.x; vy += v.y; vz += v.z; vw += v.w;
    }
    vbuf[g * 512 + u * 4 + 0] = vx;
    vbuf[g * 512 + u * 4 + 1] = vy;
    vbuf[g * 512 + u * 4 + 2] = vz;
    vbuf[g * 512 + u * 4 + 3] = vw;
    __syncthreads();
    {
      float2 o;
      o.x = vbuf[2 * t]     + vbuf[512 + 2 * t];
      o.y = vbuf[2 * t + 1] + vbuf[512 + 2 * t + 1];
      ((float2*)(out + SCR_VIN + (size_t)((hh*16 + j)*32 + b) * 512))[t] = o;
    }
    int w = t >> 6, lane = t & 63;
    #pragma unroll
    for (int k = 0; k < 4; ++k) {
      int i = w * 4 + k;
      float s = nbuf[i * 128 + lane] + nbuf[i * 128 + lane + 64];
      s = wave_reduce(s);
      if (lane == 0)
        ws[WS_NORMB + (size_t)b * 1280 + (hh*16 + j) * 16 + i] = sqrtf(s);
    }
  } else if (bid < 2592) {
    int b = bid - 2560;
    float2 a = ((const float2*)(yh + (size_t)b * 512))[t];
    float2 c = ((const float2*)(ys + (size_t)b * 512))[t];
    float d0 = c.x - a.x, d1 = c.y - a.y;
    float s = d0*d0 + d1*d1;
    s = wave_reduce(s);
    if ((t & 63) == 0) smem[t >> 6] = s;
    __syncthreads();
    if (t == 0)
      ws[WS_TVN + b] = sqrtf(smem[0]+smem[1]+smem[2]+smem[3]) * RSQ_D;
  } else if (bid == 2592) {
    float s = 0.f;
    for (int i = t; i < 4096; i += 256) {
      float4 a = ((const float4*)yh)[i], b = ((const float4*)ys)[i];
      float d0 = b.x-a.x, d1 = b.y-a.y, d2 = b.z-a.z, d3 = b.w-a.w;
      s += d0*d0 + d1*d1 + d2*d2 + d3*d3;
    }
    s = wave_reduce(s);
    if ((t & 63) == 0) smem[t >> 6] = s;
    __syncthreads();
    if (t == 0)
      out[OUT_MSE] = (smem[0]+smem[1]+smem[2]+smem[3]) * (1.f/16384.f);
  } else if (bid == 2593) {
    float s0 = 0.f, s1 = 0.f;
    #pragma unroll 4
    for (int b = 0; b < 32; ++b) {
      s0 += ys[b*512 + t]       - yh[b*512 + t];
      s1 += ys[b*512 + t + 256] - yh[b*512 + t + 256];
    }
    ws[WS_TVM + t]       = s0 * (RSQ_D / 32.f);
    ws[WS_TVM + t + 256] = s1 * (RSQ_D / 32.f);
  } else {
    // ---- Gram partials (pitch 64, R8-proven) + colsum partials of A ----
    float* tile = smem;
    float (*y0s)[64] = (float(*)[64])(smem + 8192);
    int bid0 = bid - 2594;                       // ((m*2+side)*4+slice)
    int slice = bid0 & 3, side = (bid0 >> 2) & 1, m = bid0 >> 3;
    const float* src = (side ? Bww : Aw) + (size_t)m * 32768 + slice * 8192;
    #pragma unroll
    for (int k = 0; k < 8; ++k)
      ((float4*)tile)[t + k * 256] = ((const float4*)src)[t + k * 256];
    __syncthreads();
    {
      int r = t & 63, q = t >> 6;
      float s = 0.f;
      #pragma unroll 8
      for (int dd = q * 32; dd < q * 32 + 32; ++dd) s += tile[dd * 64 + r];
      y0s[q][r] = s;
    }
    __syncthreads();
    if (side == 0 && t < 64)
      ws[WS_Y0P + (m * 4 + slice) * 64 + t] = y0s[0][t] + y0s[1][t] + y0s[2][t] + y0s[3][t];
    float acc[4][4];
    #pragma unroll
    for (int i = 0; i < 4; ++i)
      #pragma unroll
      for (int k = 0; k < 4; ++k) acc[i][k] = 0.f;
    int r1 = (t >> 4) * 4, r2 = (t & 15) * 4;
    #pragma unroll 4
    for (int dd = 0; dd < 128; ++dd) {
      float4 a1 = *(const float4*)&tile[dd * 64 + r1];
      float4 a2 = *(const float4*)&tile[dd * 64 + r2];
      float av[4] = {a1.x, a1.y, a1.z, a1.w};
      float bv[4] = {a2.x, a2.y, a2.z, a2.w};
      #pragma unroll
      for (int i = 0; i < 4; ++i)
        #pragma unroll
        for (int k = 0; k < 4; ++k) acc[i][k] += av[i] * bv[k];
    }
    float* outp = out + SCR_GP + (size_t)((m * 2 + side) * 4 + slice) * 4096;
    #pragma unroll
    for (int i = 0; i < 4; ++i) {
      float4 v; v.x = acc[i][0]; v.y = acc[i][1]; v.z = acc[i][2]; v.w = acc[i][3];
      *(float4*)&outp[(r1 + i) * 64 + r2] = v;
    }
  }
}

// ================ k_pyv: power iteration (blocks 0-79) ∥ Yv GEMV (blocks 80-239) ================
__global__ __launch_bounds__(256, 1) void k_pyv(const float* __restrict__ Bww,
    float* __restrict__ out, float* __restrict__ ws) {
  int bid = blockIdx.x, t = threadIdx.x;
  if (bid < 80) {
    if (t >= 64) return;          // power runs on wave 0 only (needs 128 VGPR live)
    int m = bid;
    int r = t;
    const float* gp = out + SCR_GP + (size_t)(m * 2 + 0) * 16384;
    const float* hp = out + SCR_GP + (size_t)(m * 2 + 1) * 16384;
    float Gc[64], Hc[64];
    #pragma unroll
    for (int c4 = 0; c4 < 16; ++c4) {
      const float* gb = gp + r * 64 + c4 * 4;
      float4 g0 = *(const float4*)(gb);
      float4 g1 = *(const float4*)(gb + 4096);
      float4 g2 = *(const float4*)(gb + 8192);
      float4 g3 = *(const float4*)(gb + 12288);
      Gc[c4*4+0] = g0.x+g1.x+g2.x+g3.x;
      Gc[c4*4+1] = g0.y+g1.y+g2.y+g3.y;
      Gc[c4*4+2] = g0.z+g1.z+g2.z+g3.z;
      Gc[c4*4+3] = g0.w+g1.w+g2.w+g3.w;
      const float* hb = hp + r * 64 + c4 * 4;
      float4 h0 = *(const float4*)(hb);
      float4 h1 = *(const float4*)(hb + 4096);
      float4 h2 = *(const float4*)(hb + 8192);
      float4 h3 = *(const float4*)(hb + 12288);
      Hc[c4*4+0] = h0.x+h1.x+h2.x+h3.x;
      Hc[c4*4+1] = h0.y+h1.y+h2.y+h3.y;
      Hc[c4*4+2] = h0.z+h1.z+h2.z+h3.z;
      Hc[c4*4+3] = h0.w+h1.w+h2.w+h3.w;
    }
    float y = (ws[WS_Y0P + (m*4+0)*64 + r] + ws[WS_Y0P + (m*4+1)*64 + r] +
               ws[WS_Y0P + (m*4+2)*64 + r] + ws[WS_Y0P + (m*4+3)*64 + r]) * RSQ_D;
    for (int it = 0; it < 20; ++it) {
      float z0 = 0.f, z1 = 0.f, z2 = 0.f, z3 = 0.f;
      #pragma unroll
      for (int c = 0; c < 16; ++c) {
        z0 = fmaf(Hc[c],      bcast_lane(y, c),      z0);
        z1 = fmaf(Hc[c + 16], bcast_lane(y, c + 16), z1);
        z2 = fmaf(Hc[c + 32], bcast_lane(y, c + 32), z2);
        z3 = fmaf(Hc[c + 48], bcast_lane(y, c + 48), z3);
      }
      float z = (z0 + z1) + (z2 + z3);
      float t0 = 0.f, t1 = 0.f, t2 = 0.f, t3 = 0.f;
      #pragma unroll
      for (int c = 0; c < 16; ++c) {
        t0 = fmaf(Gc[c],      bcast_lane(z, c),      t0);
        t1 = fmaf(Gc[c + 16], bcast_lane(z, c + 16), t1);
        t2 = fmaf(Gc[c + 32], bcast_lane(z, c + 32), t2);
        t3 = fmaf(Gc[c + 48], bcast_lane(z, c + 48), t3);
      }
      float tt = (t0 + t1) + (t2 + t3);
      float zt = z * tt;
      #pragma unroll
      for (int o = 32; o > 0; o >>= 1) zt += __shfl_xor(zt, o, 64);
      y = tt / (sqrtf(zt) + 1e-12f);
    }
    float z0 = 0.f, z1 = 0.f, z2 = 0.f, z3 = 0.f;
    #pragma unroll
    for (int c = 0; c < 16; ++c) {
      z0 = fmaf(Hc[c],      bcast_lane(y, c),      z0);
      z1 = fmaf(Hc[c + 16], bcast_lane(y, c + 16), z1);
      z2 = fmaf(Hc[c + 32], bcast_lane(y, c + 32), z2);
      z3 = fmaf(Hc[c + 48], bcast_lane(y, c + 48), z3);
    }
    float z = (z0 + z1) + (z2 + z3);
    float yz = y * z;
    #pragma unroll
    for (int o = 32; o > 0; o >>= 1) yz += __shfl_xor(yz, o, 64);
    if (r == 0)
      ws[WS_SCALE + m] = fminf(fmaxf(sqrtf(yz), SPEC_MIN), SPEC_MAX);
  } else {
    // ---- Yv = Vin @ B (lane = r, coalesced B rows, no LDS) ----
    int bid0 = bid - 80;                 // m*2 + half
    int m = bid0 >> 1, half = bid0 & 1;
    int w = t >> 6, r = t & 63;
    int b0 = half * 16 + w * 4;
    const float* Bm = Bww + (size_t)m * 32768;
    const float* Vm = out + SCR_VIN + (size_t)m * 16384;
    float acc0 = 0.f, acc1 = 0.f, acc2 = 0.f, acc3 = 0.f;
    #pragma unroll 2
    for (int d = 0; d < 512; d += 4) {
      float br0 = Bm[(d+0)*64 + r];
      float br1 = Bm[(d+1)*64 + r];
      float br2 = Bm[(d+2)*64 + r];
      float br3 = Bm[(d+3)*64 + r];
      float4 v0 = *(const float4*)(Vm + (b0+0)*512 + d);
      float4 v1 = *(const float4*)(Vm + (b0+1)*512 + d);
      float4 v2 = *(const float4*)(Vm + (b0+2)*512 + d);
      float4 v3 = *(const float4*)(Vm + (b0+3)*512 + d);
      acc0 += br0*v0.x + br1*v0.y + br2*v0.z + br3*v0.w;
      acc1 += br0*v1.x + br1*v1.y + br2*v1.z + br3*v1.w;
      acc2 += br0*v2.x + br1*v2.y + br2*v2.z + br3*v2.w;
      acc3 += br0*v3.x + br1*v3.y + br2*v3.z + br3*v3.w;
    }
    float* Yv = out + SCR_YV + (size_t)m * 2048;
    Yv[(b0+0)*64 + r] = acc0;
    Yv[(b0+1)*64 + r] = acc1;
    Yv[(b0+2)*64 + r] = acc2;
    Yv[(b0+3)*64 + r] = acc3;
  }
}

// ================ k_vw: A-rows in registers, Yv via LDS broadcast (R12 body) ================
__global__ __launch_bounds__(512) void k_vw(const float* __restrict__ Aw,
    float* __restrict__ out, float* __restrict__ ws) {
  __shared__ float ubuf[2176];   // C[1280] then Yv[32][68]
  __shared__ float gcol[512];
  __shared__ float sred[8];
  __shared__ float coefs[96];
  int m = blockIdx.x;
  int t = threadIdx.x;
  int hh = m >> 4, j = m & 15;
  const float* A1  = Aw + (size_t)m * 32768;
  const float* Vin = out + SCR_VIN + (size_t)m * 16384;
  const float* YvG = out + SCR_YV + (size_t)m * 2048;

  if (t < 256) {
    #pragma unroll
    for (int h = 0; h < 5; ++h) {
      float n = 0.f;
      #pragma unroll 8
      for (int b = 0; b < 32; ++b)
        n += ws[WS_NORMB + (size_t)b * 1280 + h * 256 + t];
      n *= (1.f / 32.f);
      float s = n;
      s += __shfl_xor(s, 1, 64);
      s += __shfl_xor(s, 2, 64);
      s += __shfl_xor(s, 4, 64);
      s += __shfl_xor(s, 8, 64);
      ubuf[h * 256 + t] = ws[WS_SCALE + h * 16 + (t >> 4)] * n / (s + 1e-9f);
    }
    if (t < 16) coefs[80 + t] = (t == 0) ? 1.f : 0.f;
  }
  __syncthreads();
  if (t < 16) {
    for (int h = 4; h >= 0; --h) {
      float s = 0.f;
      #pragma unroll
      for (int jj = 0; jj < 16; ++jj)
        s += ubuf[h * 256 + jj * 16 + t] * coefs[(h + 1) * 16 + jj];
      coefs[h * 16 + t] = s;
    }
  }
  __syncthreads();
  if (m == 0) {
    if (t < 256) {
      float tvs = 0.f;
      #pragma unroll
      for (int b = 0; b < 32; ++b) tvs += ws[WS_TVN + b];
      float tvmean = tvs * (1.f / 32.f);
      #pragma unroll
      for (int h = 0; h < 5; ++h)
        out[OUT_EDGE + h * 256 + t] = ubuf[h * 256 + t] * coefs[(h + 1) * 16 + (t >> 4)] * tvmean;
    }
    if (t < 96) ws[WS_COEF + t] = coefs[t];
  }
  float coefval = coefs[(hh + 1) * 16 + j];
  __syncthreads();

  {
    int b = t >> 4, r0 = (t & 15) * 4;
    float4 y4 = *(const float4*)(YvG + t * 4);
    *(float4*)&ubuf[b * 68 + r0] = y4;
  }
  __syncthreads();
  if (t < 64) {
    float s = 0.f;
    #pragma unroll 8
    for (int b = 0; b < 32; ++b) s += ubuf[b * 68 + t];
    ws[WS_P + m * 64 + t] = s * (1.f / 32.f);
  }
  int d = t;
  float ar[64];
  #pragma unroll
  for (int k = 0; k < 16; ++k)
    *(float4*)&ar[k * 4] = *(const float4*)(A1 + d * 64 + k * 4);
  float tmean, ssin, ssvm;
  {
    float sv = 0.f, sq = 0.f;
    #pragma unroll 4
    for (int b = 0; b < 32; ++b) {
      float v = Vin[b * 512 + d];
      sv += v; sq += v * v;
    }
    float vmean = sv * (1.f / 32.f);
    tmean = coefval * ws[WS_TVM + d];
    ws[WS_VM + m * 512 + d] = vmean;
    ssin = block_reduce_512(sq, sred) * (1.f / 32.f);
    ssvm = block_reduce_512(vmean * vmean, sred);
  }
  float gs = 0.f, vga = 0.f, fpa = 0.f;
  for (int b = 0; b < 32; ++b) {
    const float* yb = &ubuf[b * 68];
    float a0 = 0.f, a1 = 0.f, a2 = 0.f, a3 = 0.f;
    #pragma unroll
    for (int k = 0; k < 4; ++k) {
      float4 y0 = *(const float4*)&yb[k * 16 + 0];
      float4 y1 = *(const float4*)&yb[k * 16 + 4];
      float4 y2 = *(const float4*)&yb[k * 16 + 8];
      float4 y3 = *(const float4*)&yb[k * 16 + 12];
      a0 += ar[k*16+ 0]*y0.x + ar[k*16+ 1]*y0.y + ar[k*16+ 2]*y0.z + ar[k*16+ 3]*y0.w;
      a1 += ar[k*16+ 4]*y1.x + ar[k*16+ 5]*y1.y + ar[k*16+ 6]*y1.z + ar[k*16+ 7]*y1.w;
      a2 += ar[k*16+ 8]*y2.x + ar[k*16+ 9]*y2.y + ar[k*16+10]*y2.z + ar[k*16+11]*y2.w;
      a3 += ar[k*16+12]*y3.x + ar[k*16+13]*y3.y + ar[k*16+14]*y3.z + ar[k*16+15]*y3.w;
    }
    float vw = (a0 + a1) + (a2 + a3);
    float x = fminf(fmaxf(vw * 2.f, -40.f), 40.f);
    float e = __expf(x);
    float vo = (e - 1.f) / (e + 1.f);
    float fp = 1.f - vo * vo;
    gs  += vo * vo;
    vga += vo * fp;
    fpa += fp;
  }
  float goodness = block_reduce_512(gs, sred) * (1.f / 32.f);
  float delta = goodness - THETA0 * (ssin + 1e-9f);
  {
    float g = LAM_C * delta * vga * (1.f / 32.f) + LAM_R * tmean * (fpa * (1.f / 32.f));
    float gn2 = block_reduce_512(g * g, sred);
    float gnorm = sqrtf(gn2) * sqrtf(ssvm);
    float clipf = gnorm > DW_CLIP ? DW_CLIP / (gnorm + 1e-12f) : 1.f;
    float gcv = g * clipf;
    ws[WS_GC + m * 512 + d] = gcv;
    gcol[d] = gcv;
  }
  __syncthreads();
  {
    int r = t & 63, dq = t >> 6;
    float s = 0.f;
    #pragma unroll 4
    for (int k = 0; k < 64; ++k) {
      int dd = dq * 64 + k;
      s += gcol[dd] * A1[dd * 64 + r];
    }
    ubuf[dq * 64 + r] = s;
  }
  __syncthreads();
  if (t < 64) {
    float s = 0.f;
    #pragma unroll
    for (int p8 = 0; p8 < 8; ++p8) s += ubuf[p8 * 64 + t];
    ws[WS_Q + m * 64 + t] = s;
  }
}

// ================ final: T write + Adam update (float4 loads) ================
constexpr int TW_BLOCKS = 1536;
constexpr int AD_HALF4  = 655360;

__global__ __launch_bounds__(256) void k_final(const float* __restrict__ yh,
    const float* __restrict__ ys,
    const float* __restrict__ Aw, const float* __restrict__ Bww,
    const float* __restrict__ mA, const float* __restrict__ vA,
    const float* __restrict__ mB, const float* __restrict__ vB,
    const float* __restrict__ ws, float* __restrict__ out) {
  int bid = blockIdx.x, t = threadIdx.x;
  if (bid < TW_BLOCKS) {
    int g0 = (bid * 256 + t) * 4;
    int li = g0 >> 14;
    int bd = g0 & 16383;
    float4 a = *(const float4*)(yh + bd);
    float4 b = *(const float4*)(ys + bd);
    float cf = ws[WS_COEF + li] * RSQ_D;
    out[OUT_T + g0 + 0] = cf * (b.x - a.x);
    out[OUT_T + g0 + 1] = cf * (b.y - a.y);
    out[OUT_T + g0 + 2] = cf * (b.z - a.z);
    out[OUT_T + g0 + 3] = cf * (b.w - a.w);
    return;
  }
  int idx = (bid - TW_BLOCKS) * 256 + t;
  bool isB = idx >= AD_HALF4;
  int e = (isB ? idx - AD_HALF4 : idx) * 4;
  int m = e >> 15;
  int rem = e & 32767;
  int d = rem >> 6;
  int r = rem & 63;
  float4 g4;
  const float *w0, *m0, *v0;
  int obase;
  if (!isB) {
    float gc = ws[WS_GC + m * 512 + d];
    float4 p = *(const float4*)&ws[WS_P + m * 64 + r];
    g4.x = gc * p.x; g4.y = gc * p.y; g4.z = gc * p.z; g4.w = gc * p.w;
    w0 = Aw; m0 = mA; v0 = vA; obase = OUT_A;
  } else {
    float vm = ws[WS_VM + m * 512 + d];
    float4 q = *(const float4*)&ws[WS_Q + m * 64 + r];
    g4.x = vm * q.x; g4.y = vm * q.y; g4.z = vm * q.z; g4.w = vm * q.w;
    w0 = Bww; m0 = mB; v0 = vB; obase = OUT_B;
  }
  float4 a4 = *(const float4*)&w0[e];
  float4 mm4 = *(const float4*)&m0[e];
  float4 vv4 = *(const float4*)&v0[e];
  float ga[4] = {g4.x, g4.y, g4.z, g4.w};
  float aa[4] = {a4.x, a4.y, a4.z, a4.w};
  float ma[4] = {mm4.x, mm4.y, mm4.z, mm4.w};
  float va[4] = {vv4.x, vv4.y, vv4.z, vv4.w};
  #pragma unroll
  for (int i = 0; i < 4; ++i) {
    float g = ga[i];
    float mn = 0.9f * ma[i] + 0.1f * g;
    float vn = 0.999f * va[i] + 0.001f * g * g;
    float u = aa[i] - ETA_W * (mn * 10.f) / (sqrtf(vn * 1000.f) + 1e-8f);
    u = fminf(fmaxf(u, -W_MAX), W_MAX);
    out[obase + e + i] = u;
  }
}

extern "C" void kernel_launch(void* const* d_in, const int* in_sizes, int n_in,
                              void* d_out, int out_size, void* d_ws, size_t ws_size,
                              hipStream_t stream) {
  (void)in_sizes; (void)n_in; (void)out_size; (void)ws_size;
  const float* Yh = (const float*)d_in[0];
  const float* Ys = (const float*)d_in[1];
  const float* V  = (const float*)d_in[2];
  const float* Aw = (const float*)d_in[3];
  const float* Bw = (const float*)d_in[4];
  const float* mA = (const float*)d_in[5];
  const float* vA = (const float*)d_in[6];
  const float* mB = (const float*)d_in[7];
  const float* vB = (const float*)d_in[8];
  float* out = (float*)d_out;
  float* ws  = (float*)d_ws;

  k_stage1<<<2594 + 640, 256, 0, stream>>>(V, Yh, Ys, Aw, Bw, out, ws);
  k_pyv<<<240, 256, 0, stream>>>(Bw, out, ws);
  k_vw<<<80, 512, 0, stream>>>(Aw, out, ws);
  k_final<<<TW_BLOCKS + 2 * (AD_HALF4 / 256), 256, 0, stream>>>(
      Yh, Ys, Aw, Bw, mA, vA, mB, vB, ws, out);
}